// Round 7
// baseline (306.588 us; speedup 1.0000x reference)
//
#include <hip/hip_runtime.h>
#include <hip/hip_cooperative_groups.h>
#include <math.h>

// Problem constants
#define BB   32
#define CC   256
#define HH   56
#define WW   56
#define HID  512
#define RNK  8
#define HWN  (HH * WW)     // 3136
#define HW4  (HWN / 4)     // 784 float4 per (b,c) plane

__device__ __forceinline__ float gelu_exact(float v) {
    return 0.5f * v * (1.0f + erff(v * 0.70710678118654752f));
}
__device__ __forceinline__ float dot4(float4 a, float4 b) {
    return a.x * b.x + a.y * b.y + a.z * b.z + a.w * b.w;
}
__device__ __forceinline__ float wave_reduce(float d) {
    #pragma unroll
    for (int m = 32; m > 0; m >>= 1) d += __shfl_xor(d, m, 64);
    return d;
}

// ---------------------------------------------------------------------------
// Kernel 1: global average pool.  One 256-thread block per (b,c) plane.
// 103 MB read -> BW-bound.
// ---------------------------------------------------------------------------
__global__ __launch_bounds__(256) void pool_kernel(const float* __restrict__ x,
                                                   float* __restrict__ y) {
    const int bc  = blockIdx.x;
    const int tid = threadIdx.x;
    const float4* xp = reinterpret_cast<const float4*>(x) + (size_t)bc * HW4;

    float s = 0.0f;
    for (int p = tid; p < HW4; p += 256) {
        float4 v = xp[p];
        s += (v.x + v.y) + (v.z + v.w);
    }
    #pragma unroll
    for (int off = 32; off > 0; off >>= 1) s += __shfl_down(s, off, 64);

    __shared__ float ls[4];
    const int wave = tid >> 6;
    if ((tid & 63) == 0) ls[wave] = s;
    __syncthreads();
    if (tid == 0) {
        float t = (ls[0] + ls[1]) + (ls[2] + ls[3]);
        y[bc] = t * (1.0f / (float)HWN);
    }
}

// ---------------------------------------------------------------------------
// Kernel 2 (cooperative): all four MLP stages in ONE dispatch, grid.sync()
// between stages.  Wave-per-output GEMV inside each stage.
// 1024 blocks x 256 thr = 4 blocks/CU (16 waves/CU) -- safely co-residable
// (round-6 used 2048 = exact capacity and the launch was rejected).
// ---------------------------------------------------------------------------
__global__ __launch_bounds__(256) void middle_kernel(
        const float* __restrict__ y,  const float* __restrict__ w1,
        const float* __restrict__ w2, const float* __restrict__ wA,
        const float* __restrict__ wB, float* __restrict__ h,
        float* __restrict__ yp,       float* __restrict__ ab,
        float* __restrict__ attn) {
    cooperative_groups::grid_group grid = cooperative_groups::this_grid();
    const int lane   = threadIdx.x & 63;
    const int gwave  = (int)((blockIdx.x * blockDim.x + threadIdx.x) >> 6);
    const int nwaves = (int)((gridDim.x * blockDim.x) >> 6);

    // Stage 1: h[b][j] = gelu(dot(y[b], w1[j]))   -- 32*512 outputs, K=256
    for (int o = gwave; o < BB * HID; o += nwaves) {
        const int b = o >> 9;            // /512
        const int j = o & (HID - 1);
        const float4 w  = reinterpret_cast<const float4*>(w1 + (size_t)j * CC)[lane];
        const float4 iv = reinterpret_cast<const float4*>(y + (size_t)b * CC)[lane];
        float d = wave_reduce(dot4(w, iv));
        if (lane == 0) h[o] = gelu_exact(d);
    }
    grid.sync();

    // Stage 2: yp[b][i] = gelu(dot(h[b], w2[i]))  -- 32*256 outputs, K=512
    for (int o = gwave; o < BB * CC; o += nwaves) {
        const int b = o >> 8;            // /256
        const int i = o & (CC - 1);
        const float4* wr = reinterpret_cast<const float4*>(w2 + (size_t)i * HID);
        const float4* hr = reinterpret_cast<const float4*>(h + (size_t)b * HID);
        float d = wave_reduce(dot4(wr[lane], hr[lane]) +
                              dot4(wr[lane + 64], hr[lane + 64]));
        if (lane == 0) yp[o] = gelu_exact(d);
    }
    grid.sync();

    // Stage 3: ab[b][0..447]=A (h-major, RNK inner), ab[b][448..895]=Bm (r*WW+j)
    for (int o = gwave; o < BB * 896; o += nwaves) {
        const int b = o / 896;
        const int j = o - b * 896;
        const float* W = (j < 448) ? (wA + (size_t)j * CC)
                                   : (wB + (size_t)(j - 448) * CC);
        const float4 w  = reinterpret_cast<const float4*>(W)[lane];
        const float4 iv = reinterpret_cast<const float4*>(yp + (size_t)b * CC)[lane];
        float d = wave_reduce(dot4(w, iv));
        if (lane == 0) ab[o] = d;
    }
    grid.sync();

    // Stage 4: attn[b][p] = sigmoid(sum_r A[b][i][r]*Bm[b][r][j])  (thread/elem)
    const int tg   = (int)(blockIdx.x * blockDim.x + threadIdx.x);
    const int nthr = (int)(gridDim.x * blockDim.x);
    for (int idx = tg; idx < BB * HWN; idx += nthr) {
        const int b = idx / HWN;
        const int p = idx - b * HWN;
        const int i = p / WW;
        const int j = p - i * WW;
        const float* A  = ab + (size_t)b * 896 + i * RNK;
        const float* Bm = ab + (size_t)b * 896 + 448 + j;
        float m = 0.0f;
        #pragma unroll
        for (int r = 0; r < RNK; ++r) m += A[r] * Bm[r * WW];
        attn[idx] = 1.0f / (1.0f + expf(-m));
    }
}

// ---------------------------------------------------------------------------
// Fallback path (round-4 proven): separate wave-per-output GEMV dispatches.
// ---------------------------------------------------------------------------
template <int K, int J, bool GELU>
__global__ __launch_bounds__(256) void gemv_kernel(const float* __restrict__ in,
                                                   const float* __restrict__ W,
                                                   float* __restrict__ out) {
    const int lane = threadIdx.x & 63;
    const int wid  = (blockIdx.x * 256 + threadIdx.x) >> 6;
    const int b = wid / J;
    const int j = wid - b * J;
    const float4* wr = reinterpret_cast<const float4*>(W  + (size_t)j * K);
    const float4* ir = reinterpret_cast<const float4*>(in + (size_t)b * K);
    float d;
    if constexpr (K == 256) {
        d = dot4(wr[lane], ir[lane]);
    } else {
        d = dot4(wr[lane], ir[lane]) + dot4(wr[lane + 64], ir[lane + 64]);
    }
    d = wave_reduce(d);
    if (lane == 0) out[(size_t)b * J + j] = GELU ? gelu_exact(d) : d;
}

__global__ __launch_bounds__(256) void gemv_ab_kernel(const float* __restrict__ yp,
                                                      const float* __restrict__ wA,
                                                      const float* __restrict__ wB,
                                                      float* __restrict__ ab) {
    const int lane = threadIdx.x & 63;
    const int wid  = (blockIdx.x * 256 + threadIdx.x) >> 6;
    const int b = wid / 896;
    const int j = wid - b * 896;
    const float* W = (j < 448) ? (wA + (size_t)j * CC)
                               : (wB + (size_t)(j - 448) * CC);
    const float4* wr = reinterpret_cast<const float4*>(W);
    const float4* ir = reinterpret_cast<const float4*>(yp + (size_t)b * CC);
    float d = wave_reduce(dot4(wr[lane], ir[lane]));
    if (lane == 0) ab[(size_t)b * 896 + j] = d;
}

__global__ __launch_bounds__(256) void attnmap_kernel(const float* __restrict__ ab,
                                                      float* __restrict__ attn) {
    const int idx = blockIdx.x * 256 + threadIdx.x;
    const int b = idx / HWN;
    const int p = idx - b * HWN;
    const int i = p / WW;
    const int j = p - i * WW;
    const float* A  = ab + (size_t)b * 896 + i * RNK;
    const float* Bm = ab + (size_t)b * 896 + 448 + j;
    float m = 0.0f;
    #pragma unroll
    for (int r = 0; r < RNK; ++r) m += A[r] * Bm[r * WW];
    attn[idx] = 1.0f / (1.0f + expf(-m));
}

// ---------------------------------------------------------------------------
// Kernel 3: broadcast attn (B,H,W) across C -> out (B,C,H,W).  Write-bound.
// ---------------------------------------------------------------------------
__global__ __launch_bounds__(256) void bcast_kernel(const float* __restrict__ attn,
                                                    float4* __restrict__ out) {
    const unsigned total  = (unsigned)BB * CC * HW4;   // 6,422,528 float4
    const unsigned stride = gridDim.x * blockDim.x;
    const float4* ap = reinterpret_cast<const float4*>(attn);
    for (unsigned idx = blockIdx.x * blockDim.x + threadIdx.x; idx < total;
         idx += stride) {
        const unsigned b = idx / (CC * HW4);
        const unsigned p = idx % HW4;
        out[idx] = ap[b * HW4 + p];
    }
}

// ---------------------------------------------------------------------------
extern "C" void kernel_launch(void* const* d_in, const int* in_sizes, int n_in,
                              void* d_out, int out_size, void* d_ws, size_t ws_size,
                              hipStream_t stream) {
    const float* x  = (const float*)d_in[0];
    const float* w1 = (const float*)d_in[1];
    const float* w2 = (const float*)d_in[2];
    const float* wA = (const float*)d_in[3];
    const float* wB = (const float*)d_in[4];
    float* out = (float*)d_out;

    // ws layout (floats): y[B*C] | h[B*HID] | yp[B*C] | ab[B*896] | attn[B*HWN]
    float* y    = (float*)d_ws;
    float* h    = y  + BB * CC;         // 8192
    float* yp   = h  + BB * HID;        // 16384
    float* ab   = yp + BB * CC;         // 8192
    float* attn = ab + BB * 896;        // 28672

    pool_kernel<<<BB * CC, 256, 0, stream>>>(x, y);

    void* args[] = {(void*)&y, (void*)&w1, (void*)&w2, (void*)&wA, (void*)&wB,
                    (void*)&h, (void*)&yp, (void*)&ab, (void*)&attn};
    hipError_t cerr = hipLaunchCooperativeKernel((const void*)middle_kernel,
                                                 dim3(1024), dim3(256),
                                                 args, 0, stream);
    if (cerr != hipSuccess) {
        // Fallback: proven 4-dispatch chain (round-4 structure, 52.4 us total)
        gemv_kernel<CC, HID, true><<<(BB * HID) / 4, 256, 0, stream>>>(y, w1, h);
        gemv_kernel<HID, CC, true><<<(BB * CC) / 4, 256, 0, stream>>>(h, w2, yp);
        gemv_ab_kernel<<<(BB * 896) / 4, 256, 0, stream>>>(yp, wA, wB, ab);
        attnmap_kernel<<<(BB * HWN) / 256, 256, 0, stream>>>(ab, attn);
    }

    bcast_kernel<<<2048, 256, 0, stream>>>(attn, reinterpret_cast<float4*>(out));
}

// Round 8
// 61.723 us; speedup vs baseline: 4.9672x; 4.9672x over previous
//
#include <hip/hip_runtime.h>
#include <math.h>

// Problem constants
#define BB   32
#define CC   256
#define HH   56
#define WW   56
#define HID  512
#define RNK  8
#define HWN  (HH * WW)     // 3136
#define HW4  (HWN / 4)     // 784 float4 per (b,c) plane

__device__ __forceinline__ float gelu_exact(float v) {
    return 0.5f * v * (1.0f + erff(v * 0.70710678118654752f));
}
__device__ __forceinline__ float dot4(float4 a, float4 b) {
    return a.x * b.x + a.y * b.y + a.z * b.z + a.w * b.w;
}

// ---------------------------------------------------------------------------
// Kernel 1: global average pool.  One 256-thread block per (b,c) plane.
// 103 MB read -> BW-bound, ~15 us.
// ---------------------------------------------------------------------------
__global__ __launch_bounds__(256) void pool_kernel(const float* __restrict__ x,
                                                   float* __restrict__ y) {
    const int bc  = blockIdx.x;
    const int tid = threadIdx.x;
    const float4* xp = reinterpret_cast<const float4*>(x) + (size_t)bc * HW4;

    float s = 0.0f;
    for (int p = tid; p < HW4; p += 256) {
        float4 v = xp[p];
        s += (v.x + v.y) + (v.z + v.w);
    }
    #pragma unroll
    for (int off = 32; off > 0; off >>= 1) s += __shfl_down(s, off, 64);

    __shared__ float ls[4];
    const int wave = tid >> 6;
    if ((tid & 63) == 0) ls[wave] = s;
    __syncthreads();
    if (tid == 0) {
        float t = (ls[0] + ls[1]) + (ls[2] + ls[3]);
        y[bc] = t * (1.0f / (float)HWN);
    }
}

// ---------------------------------------------------------------------------
// Kernel 2: ALL middle stages in one plain dispatch.  Block-per-batch
// (32 blocks x 1024 thr), intermediates in LDS, __syncthreads between stages.
//
// Layout: each wave is four 16-lane groups; each group owns one GEMV row,
// so 4 rows are in flight per wave (64 rows per block-pass).  Each lane loads
// 4-8 independent float4s (pipelined in the VMEM queue) and the reduction is
// only 4 shfl_xor steps (masks 1,2,4,8 stay inside the 16-lane group).  This
// breaks the ~1600cy serial-row-per-wave latency wall measured in rounds 2/3
// (one row per wave at a time = 70+ us for the same work).
// ---------------------------------------------------------------------------
__global__ __launch_bounds__(1024) void middle_kernel(
        const float* __restrict__ y,  const float* __restrict__ w1,
        const float* __restrict__ w2, const float* __restrict__ wA,
        const float* __restrict__ wB, float* __restrict__ attn) {
    const int b    = blockIdx.x;       // 0 .. B-1
    const int tid  = threadIdx.x;      // 0 .. 1023
    const int wv   = tid >> 6;         // wave 0..15
    const int lane = tid & 63;
    const int sub  = lane & 15;        // position within 16-lane group
    const int rg   = lane >> 4;        // row-in-group 0..3

    __shared__ float y_s[CC];          // 1 KB
    __shared__ float h_s[HID];         // 2 KB
    __shared__ float yp_s[CC];         // 1 KB
    __shared__ float ab_s[896];        // 3.5 KB: [0,448)=A (h*8+r), [448,896)=Bm (r*56+j)

    if (tid < CC) y_s[tid] = y[b * CC + tid];
    __syncthreads();

    // Stage 1: h[j] = gelu(dot(y, w1[j]))  -- 512 rows, K=256, 8 block-passes
    {
        const float4* ys4 = reinterpret_cast<const float4*>(y_s);
        const float4 yv0 = ys4[sub],      yv1 = ys4[sub + 16],
                     yv2 = ys4[sub + 32], yv3 = ys4[sub + 48];
        for (int row = wv * 4 + rg; row < HID; row += 64) {
            const float4* wr = reinterpret_cast<const float4*>(w1 + (size_t)row * CC);
            float d = dot4(wr[sub], yv0)      + dot4(wr[sub + 16], yv1)
                    + dot4(wr[sub + 32], yv2) + dot4(wr[sub + 48], yv3);
            #pragma unroll
            for (int m = 8; m > 0; m >>= 1) d += __shfl_xor(d, m, 64);
            if (sub == 0) h_s[row] = gelu_exact(d);
        }
    }
    __syncthreads();

    // Stage 2: yp[i] = gelu(dot(h, w2[i])) -- 256 rows, K=512, 4 block-passes
    {
        const float4* hs4 = reinterpret_cast<const float4*>(h_s);
        float4 hv[8];
        #pragma unroll
        for (int k = 0; k < 8; ++k) hv[k] = hs4[sub + 16 * k];
        for (int row = wv * 4 + rg; row < CC; row += 64) {
            const float4* wr = reinterpret_cast<const float4*>(w2 + (size_t)row * HID);
            float d = 0.0f;
            #pragma unroll
            for (int k = 0; k < 8; ++k) d += dot4(wr[sub + 16 * k], hv[k]);
            #pragma unroll
            for (int m = 8; m > 0; m >>= 1) d += __shfl_xor(d, m, 64);
            if (sub == 0) yp_s[row] = gelu_exact(d);
        }
    }
    __syncthreads();

    // Stage 3: ab rows 0..447 = wA rows (A, h-major r-inner);
    //          rows 448..895 = wB rows (Bm, r*56+j).  K=256, 14 block-passes.
    // 448 % 64 == 0, so the wA/wB switch never splits a wave (uniform branch).
    {
        const float4* ps4 = reinterpret_cast<const float4*>(yp_s);
        const float4 pv0 = ps4[sub],      pv1 = ps4[sub + 16],
                     pv2 = ps4[sub + 32], pv3 = ps4[sub + 48];
        for (int row = wv * 4 + rg; row < 896; row += 64) {
            const float* W = (row < 448) ? (wA + (size_t)row * CC)
                                         : (wB + (size_t)(row - 448) * CC);
            const float4* wr = reinterpret_cast<const float4*>(W);
            float d = dot4(wr[sub], pv0)      + dot4(wr[sub + 16], pv1)
                    + dot4(wr[sub + 32], pv2) + dot4(wr[sub + 48], pv3);
            #pragma unroll
            for (int m = 8; m > 0; m >>= 1) d += __shfl_xor(d, m, 64);
            if (sub == 0) ab_s[row] = d;
        }
    }
    __syncthreads();

    // Stage 4: attn[p] = sigmoid(sum_r A[i][r]*Bm[r][j]), 3136 elems, LDS-fed.
    for (int p = tid; p < HWN; p += 1024) {
        const int i = p / WW;
        const int j = p - i * WW;
        float m = 0.0f;
        #pragma unroll
        for (int r = 0; r < RNK; ++r) m += ab_s[i * RNK + r] * ab_s[448 + r * WW + j];
        attn[(size_t)b * HWN + p] = 1.0f / (1.0f + expf(-m));
    }
}

// ---------------------------------------------------------------------------
// Kernel 3: broadcast attn (B,H,W) across C -> out (B,C,H,W).  Write-bound.
// ---------------------------------------------------------------------------
__global__ __launch_bounds__(256) void bcast_kernel(const float* __restrict__ attn,
                                                    float4* __restrict__ out) {
    const unsigned total  = (unsigned)BB * CC * HW4;   // 6,422,528 float4
    const unsigned stride = gridDim.x * blockDim.x;
    const float4* ap = reinterpret_cast<const float4*>(attn);
    for (unsigned idx = blockIdx.x * blockDim.x + threadIdx.x; idx < total;
         idx += stride) {
        const unsigned b = idx / (CC * HW4);
        const unsigned p = idx % HW4;
        out[idx] = ap[b * HW4 + p];
    }
}

// ---------------------------------------------------------------------------
extern "C" void kernel_launch(void* const* d_in, const int* in_sizes, int n_in,
                              void* d_out, int out_size, void* d_ws, size_t ws_size,
                              hipStream_t stream) {
    const float* x  = (const float*)d_in[0];
    const float* w1 = (const float*)d_in[1];
    const float* w2 = (const float*)d_in[2];
    const float* wA = (const float*)d_in[3];
    const float* wB = (const float*)d_in[4];
    float* out = (float*)d_out;

    // ws layout (floats): y[B*C] | attn[B*HWN]
    float* y    = (float*)d_ws;
    float* attn = y + BB * CC;

    pool_kernel<<<BB * CC, 256, 0, stream>>>(x, y);
    middle_kernel<<<BB, 1024, 0, stream>>>(y, w1, w2, wA, wB, attn);
    bcast_kernel<<<2048, 256, 0, stream>>>(attn, reinterpret_cast<float4*>(out));
}

// Round 9
// 52.463 us; speedup vs baseline: 5.8439x; 1.1765x over previous
//
#include <hip/hip_runtime.h>
#include <math.h>

// Problem constants
#define BB   32
#define CC   256
#define HH   56
#define WW   56
#define HID  512
#define RNK  8
#define HWN  (HH * WW)     // 3136
#define HW4  (HWN / 4)     // 784 float4 per (b,c) plane

__device__ __forceinline__ float gelu_exact(float v) {
    return 0.5f * v * (1.0f + erff(v * 0.70710678118654752f));
}
__device__ __forceinline__ float dot4(float4 a, float4 b) {
    return a.x * b.x + a.y * b.y + a.z * b.z + a.w * b.w;
}

// ---------------------------------------------------------------------------
// Kernel 1: global average pool.  One 256-thread block per (b,c) plane.
// 103 MB read -> BW-bound.
// ---------------------------------------------------------------------------
__global__ __launch_bounds__(256) void pool_kernel(const float* __restrict__ x,
                                                   float* __restrict__ y) {
    const int bc  = blockIdx.x;
    const int tid = threadIdx.x;
    const float4* xp = reinterpret_cast<const float4*>(x) + (size_t)bc * HW4;

    float s = 0.0f;
    for (int p = tid; p < HW4; p += 256) {
        float4 v = xp[p];
        s += (v.x + v.y) + (v.z + v.w);
    }
    #pragma unroll
    for (int off = 32; off > 0; off >>= 1) s += __shfl_down(s, off, 64);

    __shared__ float ls[4];
    const int wave = tid >> 6;
    if ((tid & 63) == 0) ls[wave] = s;
    __syncthreads();
    if (tid == 0) {
        float t = (ls[0] + ls[1]) + (ls[2] + ls[3]);
        y[bc] = t * (1.0f / (float)HWN);
    }
}

// ---------------------------------------------------------------------------
// Kernel 2: stages 1-3, GPU-WIDE via redundant slicing.
// 256 blocks = 8 slices per batch.  Every block redundantly computes the
// full h and yp for its batch in LDS (weights are L2-resident; the extra
// reads are ~1 MB/block), then computes ITS 112-row slice of ab (written
// exactly once).  Rows use 8-lane groups (8 independent float4 loads per
// lane in flight, 3-step shuffle reduce) -> 9 dependent passes per block
// on 256 CUs, vs round-8's 26 passes on 32 CUs (~38 us, latency-bound).
// ---------------------------------------------------------------------------
__global__ __launch_bounds__(1024) void middle_kernel(
        const float* __restrict__ y,  const float* __restrict__ w1,
        const float* __restrict__ w2, const float* __restrict__ wA,
        const float* __restrict__ wB, float* __restrict__ ab) {
    const int b     = blockIdx.x >> 3;    // batch 0..31
    const int slice = blockIdx.x & 7;     // 0..7
    const int tid   = threadIdx.x;        // 0..1023

    __shared__ float y_s[CC];
    __shared__ float h_s[HID];
    __shared__ float yp_s[CC];

    if (tid < CC) y_s[tid] = y[b * CC + tid];
    __syncthreads();

    // Stage 1: h[j] = gelu(dot(y, w1[j])), 512 rows, K=256.
    // 8 lanes/row -> 128 rows/pass -> 4 passes; 8 float4 loads/lane.
    {
        const int sub = tid & 7;          // lane within row group
        const int rg  = tid >> 3;         // row group 0..127
        const float4* ys4 = reinterpret_cast<const float4*>(y_s);
        float4 yv[8];
        #pragma unroll
        for (int k = 0; k < 8; ++k) yv[k] = ys4[sub + 8 * k];
        #pragma unroll
        for (int pass = 0; pass < 4; ++pass) {
            const int row = pass * 128 + rg;
            const float4* wr = reinterpret_cast<const float4*>(w1 + (size_t)row * CC);
            float d = 0.0f;
            #pragma unroll
            for (int k = 0; k < 8; ++k) d += dot4(wr[sub + 8 * k], yv[k]);
            d += __shfl_xor(d, 1, 64);
            d += __shfl_xor(d, 2, 64);
            d += __shfl_xor(d, 4, 64);
            if (sub == 0) h_s[row] = gelu_exact(d);
        }
    }
    __syncthreads();

    // Stage 2: yp[i] = gelu(dot(h, w2[i])), 256 rows, K=512.
    // 16 lanes/row -> 64 rows/pass -> 4 passes; 8 float4 loads/lane.
    {
        const int sub = tid & 15;
        const int rg  = tid >> 4;         // 0..63
        const float4* hs4 = reinterpret_cast<const float4*>(h_s);
        float4 hv[8];
        #pragma unroll
        for (int k = 0; k < 8; ++k) hv[k] = hs4[sub + 16 * k];
        #pragma unroll
        for (int pass = 0; pass < 4; ++pass) {
            const int row = pass * 64 + rg;
            const float4* wr = reinterpret_cast<const float4*>(w2 + (size_t)row * HID);
            float d = 0.0f;
            #pragma unroll
            for (int k = 0; k < 8; ++k) d += dot4(wr[sub + 16 * k], hv[k]);
            d += __shfl_xor(d, 1, 64);
            d += __shfl_xor(d, 2, 64);
            d += __shfl_xor(d, 4, 64);
            d += __shfl_xor(d, 8, 64);
            if (sub == 0) yp_s[row] = gelu_exact(d);
        }
    }
    __syncthreads();

    // Stage 3: this block's 112-row slice of ab (rows slice*112 .. +111).
    // Global row r<448 -> A row r of wA; r>=448 -> Bm row r-448 of wB.
    // slice*112 keeps the wA/wB choice uniform per block (448 = 4*112).
    // 8 lanes/row -> 1 pass (rg<112); K=256.
    {
        const int sub = tid & 7;
        const int rg  = tid >> 3;         // 0..127, use <112
        if (rg < 112) {
            const int row = slice * 112 + rg;
            const float* W = (row < 448) ? (wA + (size_t)row * CC)
                                         : (wB + (size_t)(row - 448) * CC);
            const float4* wr  = reinterpret_cast<const float4*>(W);
            const float4* ps4 = reinterpret_cast<const float4*>(yp_s);
            float d = 0.0f;
            #pragma unroll
            for (int k = 0; k < 8; ++k) d += dot4(wr[sub + 8 * k], ps4[sub + 8 * k]);
            d += __shfl_xor(d, 1, 64);
            d += __shfl_xor(d, 2, 64);
            d += __shfl_xor(d, 4, 64);
            if (sub == 0) ab[(size_t)b * 896 + row] = d;
        }
    }
}

// ---------------------------------------------------------------------------
// Kernel 3: stage 4 + broadcast fused.  256 blocks = 8 slices per batch.
// Each block loads ab[b] (3.6 KB), computes the 3136-elem sigmoid map ONCE
// into LDS (attn computed 8x/batch total = 803K sigmoids, vs round-5's
// per-output disaster of 25.7M), then streams its 32 channel planes out.
// Write-bound: 103 MB total.
// ---------------------------------------------------------------------------
__global__ __launch_bounds__(1024) void bcast_map_kernel(
        const float* __restrict__ ab, float4* __restrict__ out) {
    const int b     = blockIdx.x >> 3;    // batch
    const int slice = blockIdx.x & 7;     // channel slice (32 channels)
    const int tid   = threadIdx.x;

    __shared__ float ab_s[896];
    __shared__ float attn_s[HWN];         // 12.5 KB

    if (tid < 896) ab_s[tid] = ab[(size_t)b * 896 + tid];
    __syncthreads();

    for (int p = tid; p < HWN; p += 1024) {
        const int i = p / WW;
        const int j = p - i * WW;
        float m = 0.0f;
        #pragma unroll
        for (int r = 0; r < RNK; ++r)
            m += ab_s[i * RNK + r] * ab_s[448 + r * WW + j];
        attn_s[p] = 1.0f / (1.0f + expf(-m));
    }
    __syncthreads();

    const float4* a4 = reinterpret_cast<const float4*>(attn_s);
    float4* base = out + ((size_t)(b * CC + slice * 32)) * HW4;
    // 32 planes x 784 float4 = 25088 stores, consecutive across threads.
    for (int idx = tid; idx < 32 * HW4; idx += 1024) {
        const int p = idx % HW4;
        base[idx] = a4[p];
    }
}

// ---------------------------------------------------------------------------
extern "C" void kernel_launch(void* const* d_in, const int* in_sizes, int n_in,
                              void* d_out, int out_size, void* d_ws, size_t ws_size,
                              hipStream_t stream) {
    const float* x  = (const float*)d_in[0];
    const float* w1 = (const float*)d_in[1];
    const float* w2 = (const float*)d_in[2];
    const float* wA = (const float*)d_in[3];
    const float* wB = (const float*)d_in[4];
    float* out = (float*)d_out;

    // ws layout (floats): y[B*C] | ab[B*896]
    float* y  = (float*)d_ws;
    float* ab = y + BB * CC;

    pool_kernel<<<BB * CC, 256, 0, stream>>>(x, y);
    middle_kernel<<<BB * 8, 1024, 0, stream>>>(y, w1, w2, wA, wB, ab);
    bcast_map_kernel<<<BB * 8, 1024, 0, stream>>>(ab, reinterpret_cast<float4*>(out));
}